// Round 2
// baseline (445.214 us; speedup 1.0000x reference)
//
#include <hip/hip_runtime.h>
#include <math.h>

// ---- problem constants ----
constexpr int kH    = 1024;  // GRU hidden
constexpr int kZ    = 1024;  // latent z
constexpr int kA    = 4;     // action dim
constexpr int kF    = 30;    // experts / horizon
constexpr int kDIN  = 2048;  // expert in (Z+H)
constexpr int kDH   = 512;   // expert hidden
constexpr int kEIN  = 1118;  // eval in (H + 94)
constexpr int kEH   = 512;   // eval hidden
constexpr int kEOUT = 94;    // eval out

// persistent GRU geometry
constexpr int NB  = 64;    // blocks (co-resident on 256-CU chip)
constexpr int BT  = 1024;  // threads per block (16 waves)
constexpr int JPB = 16;    // hidden rows per block (1 per wave)

// workspace layout (floats)
constexpr size_t AGRU_OFF = 0;                            // kF*kH
constexpr size_t HACC_OFF = AGRU_OFF + (size_t)kF * kH;   // kF*2*kDH
constexpr size_t EHA_OFF  = HACC_OFF + (size_t)kF * 2 * kDH;  // kEH
constexpr size_t BAR_OFF  = EHA_OFF + kEH;                // 1 (unsigned)

__device__ __forceinline__ float sigmoidf_(float x) { return 1.0f / (1.0f + __expf(-x)); }

__device__ __forceinline__ float wave_reduce(float v) {
#pragma unroll
  for (int off = 32; off > 0; off >>= 1) v += __shfl_down(v, off, 64);
  return v;
}

// ---------------- persistent GRU: one launch for all 30 steps ----------------
__global__ __launch_bounds__(BT) void gru_persist(const float* __restrict__ Whh,
                                                  const float* __restrict__ bhh,
                                                  const float* __restrict__ Wih,
                                                  const float* __restrict__ bih,
                                                  const float* __restrict__ a_t,
                                                  const float* __restrict__ b_t,
                                                  float* __restrict__ agru,
                                                  unsigned* __restrict__ bar,
                                                  const int* __restrict__ fptr) {
  const int tid  = threadIdx.x;
  const int wave = tid >> 6;
  const int lane = tid & 63;
  const int j    = blockIdx.x * JPB + wave;  // this wave's hidden row, 0..1023
  const int f    = *fptr;

  // --- weight fragments: rows j, j+H, j+2H of Whh, 48 floats/lane in VGPRs ---
  const float4* W4 = (const float4*)Whh;
  float4 wr[4], wz[4], wn[4];
#pragma unroll
  for (int i = 0; i < 4; i++) {
    wr[i] = W4[(size_t)j * 256 + i * 64 + lane];
    wz[i] = W4[(size_t)(j + kH) * 256 + i * 64 + lane];
    wn[i] = W4[(size_t)(j + 2 * kH) * 256 + i * 64 + lane];
  }
  const float bhr = bhh[j];
  const float bhz = bhh[j + kH];
  const float bhn = bhh[j + 2 * kH];

  // --- gi[t][wave][gate] precompute into LDS (off critical path) ---
  __shared__ float gis[kF][JPB][3];
  __shared__ __align__(16) float hs[kH];
  for (int idx = tid; idx < kF * JPB * 3; idx += BT) {
    int t = idx / (JPB * 3);
    int rem = idx - t * (JPB * 3);
    int w = rem / 3, g = rem - w * 3;
    int r = blockIdx.x * JPB + w + g * kH;
    float acc = bih[r];
    const float* wih = Wih + (size_t)r * kA;
    const float* at  = a_t + (size_t)t * kA;
#pragma unroll
    for (int k = 0; k < kA; k++) acc += wih[k] * at[k];
    gis[t][w][g] = acc;
  }
  __syncthreads();

  const float4* hs4 = (const float4*)hs;

  for (int t = 0; t < f; t++) {
    // phase A: stage h_prev (device-fresh) into LDS, one element per thread
    const float* hsrc = (t == 0) ? b_t : (agru + (size_t)(t - 1) * kH);
    hs[tid] = __hip_atomic_load(hsrc + tid, __ATOMIC_RELAXED, __HIP_MEMORY_SCOPE_AGENT);
    __syncthreads();

    // phase B: 3 dot products (48 MACs/lane) + reduce + gates
    float accr = 0.f, accz = 0.f, accn = 0.f;
#pragma unroll
    for (int i = 0; i < 4; i++) {
      float4 h4 = hs4[i * 64 + lane];
      accr += wr[i].x * h4.x + wr[i].y * h4.y + wr[i].z * h4.z + wr[i].w * h4.w;
      accz += wz[i].x * h4.x + wz[i].y * h4.y + wz[i].z * h4.z + wz[i].w * h4.w;
      accn += wn[i].x * h4.x + wn[i].y * h4.y + wn[i].z * h4.z + wn[i].w * h4.w;
    }
    accr = wave_reduce(accr);
    accz = wave_reduce(accz);
    accn = wave_reduce(accn);

    if (lane == 0) {
      float rg = sigmoidf_(gis[t][wave][0] + accr + bhr);
      float zg = sigmoidf_(gis[t][wave][1] + accz + bhz);
      float ng = tanhf(gis[t][wave][2] + rg * (accn + bhn));
      float hnew = (1.0f - zg) * ng + zg * hs[j];
      __hip_atomic_store(agru + (size_t)t * kH + j, hnew, __ATOMIC_RELAXED,
                         __HIP_MEMORY_SCOPE_AGENT);
    }

    // phase C: grid barrier (monotonic counter, release-sequence RMWs)
    __syncthreads();
    if (tid == 0) {
      __threadfence();
      __hip_atomic_fetch_add(bar, 1u, __ATOMIC_ACQ_REL, __HIP_MEMORY_SCOPE_AGENT);
      const unsigned target = (unsigned)NB * (unsigned)(t + 1);
      while (__hip_atomic_load(bar, __ATOMIC_ACQUIRE, __HIP_MEMORY_SCOPE_AGENT) < target) {
        __builtin_amdgcn_s_sleep(1);
      }
    }
    __syncthreads();
  }
}

// ---------------- stage1: expert first layers + eval first layer ----------------
constexpr int EXP_SPLIT  = 8;  // blocks per expert, 256 K-rows each
constexpr int EVAL_SPLIT = 8;  // blocks for eval, 140 K-rows each

__global__ __launch_bounds__(512) void stage1(const float* __restrict__ zpos,
                                              const float* __restrict__ zneg,
                                              const float* __restrict__ agru,
                                              const float* __restrict__ W1,
                                              const float* __restrict__ b_t,
                                              const float* __restrict__ ipo,
                                              const float* __restrict__ eW1,
                                              float* __restrict__ hacc,
                                              float* __restrict__ ehacc,
                                              const int* __restrict__ fptr) {
  int b = blockIdx.x;
  int tid = threadIdx.x;

  if (b < kF * EXP_SPLIT) {
    __shared__ float xs_p[256];
    __shared__ float xs_n[256];
    int i = b >> 3;
    int part = b & 7;
    if (i >= *fptr) return;
    int r0 = part * 256;
    if (tid < 256) {
      int r = r0 + tid;
      float xp, xn;
      if (r < kZ) { xp = zpos[(size_t)i * kZ + r]; xn = zneg[(size_t)i * kZ + r]; }
      else        { float v = agru[(size_t)i * kH + (r - kZ)]; xp = v; xn = v; }
      xs_p[tid] = xp;
      xs_n[tid] = xn;
    }
    __syncthreads();
    float ap = 0.f, an = 0.f;
    const float* w = W1 + ((size_t)i * kDIN + r0) * kDH + tid;
#pragma unroll 4
    for (int r = 0; r < 256; r++) {
      float wv = w[(size_t)r * kDH];
      ap += xs_p[r] * wv;
      an += xs_n[r] * wv;
    }
    atomicAdd(&hacc[((size_t)i * 2 + 0) * kDH + tid], ap);
    atomicAdd(&hacc[((size_t)i * 2 + 1) * kDH + tid], an);
  } else {
    // eval first layer
    __shared__ float xs[140];
    int part = b - kF * EXP_SPLIT;  // 0..7
    int r0 = part * 140;
    int nrows = min(140, kEIN - r0);
    if (tid < nrows) {
      int r = r0 + tid;
      xs[tid] = (r < kH) ? b_t[r] : ipo[r - kH];
    }
    __syncthreads();
    float acc = 0.f;
    const float* w = eW1 + (size_t)r0 * kEH + tid;
    for (int r = 0; r < nrows; r++) acc += xs[r] * w[(size_t)r * kEH];
    atomicAdd(&ehacc[tid], acc);
  }
}

// ---------------- stage2: second layers + activations -> 2f+94 outputs ----------------
__global__ __launch_bounds__(512) void stage2(const float* __restrict__ hacc,
                                              const float* __restrict__ ehacc,
                                              const float* __restrict__ b1,
                                              const float* __restrict__ W2,
                                              const float* __restrict__ b2,
                                              const float* __restrict__ eb1,
                                              const float* __restrict__ eW2,
                                              const float* __restrict__ eb2,
                                              float* __restrict__ out,
                                              const int* __restrict__ fptr) {
  int b = blockIdx.x;
  int tid = threadIdx.x;
  int f = *fptr;
  if (b < kF) {
    int i = b;
    if (i >= f) return;
    float bias = b1[(size_t)i * kDH + tid];
    float hp = fmaxf(hacc[((size_t)i * 2 + 0) * kDH + tid] + bias, 0.f);
    float hn = fmaxf(hacc[((size_t)i * 2 + 1) * kDH + tid] + bias, 0.f);
    float w = W2[(size_t)i * kDH + tid];
    float pp = wave_reduce(hp * w);
    float pn = wave_reduce(hn * w);
    __shared__ float redp[8];
    __shared__ float redn[8];
    int wave = tid >> 6, lane = tid & 63;
    if (lane == 0) { redp[wave] = pp; redn[wave] = pn; }
    __syncthreads();
    if (tid == 0) {
      float sp = 0.f, sn = 0.f;
#pragma unroll
      for (int k = 0; k < 8; k++) { sp += redp[k]; sn += redn[k]; }
      out[i] = sp + b2[i];
      out[f + i] = sn + b2[i];
    }
  } else {
    // eval second layer: 94 outputs
    if (tid < kEOUT) {
      float acc = eb2[tid];
      for (int h = 0; h < kEH; h++) {
        float eh = fmaxf(ehacc[h] + eb1[h], 0.f);
        acc += eh * eW2[(size_t)h * kEOUT + tid];
      }
      out[2 * f + tid] = sigmoidf_(acc);
    }
  }
}

extern "C" void kernel_launch(void* const* d_in, const int* in_sizes, int n_in,
                              void* d_out, int out_size, void* d_ws, size_t ws_size,
                              hipStream_t stream) {
  const float* b_t  = (const float*)d_in[0];
  const float* a_t  = (const float*)d_in[1];
  const float* zpos = (const float*)d_in[2];
  const float* zneg = (const float*)d_in[3];
  const float* ipo  = (const float*)d_in[4];
  const float* gWih = (const float*)d_in[5];
  const float* gWhh = (const float*)d_in[6];
  const float* gbih = (const float*)d_in[7];
  const float* gbhh = (const float*)d_in[8];
  const float* mW1  = (const float*)d_in[9];
  const float* mb1  = (const float*)d_in[10];
  const float* mW2  = (const float*)d_in[11];
  const float* mb2  = (const float*)d_in[12];
  const float* eW1  = (const float*)d_in[13];
  const float* eb1  = (const float*)d_in[14];
  const float* eW2  = (const float*)d_in[15];
  const float* eb2  = (const float*)d_in[16];
  const int*   fptr = (const int*)d_in[17];

  float* ws    = (float*)d_ws;
  float* agru  = ws + AGRU_OFF;
  float* hacc  = ws + HACC_OFF;
  float* ehacc = ws + EHA_OFF;
  unsigned* bar = (unsigned*)(ws + BAR_OFF);
  float* out   = (float*)d_out;

  // zero accumulators + barrier counter (contiguous region)
  hipMemsetAsync(hacc, 0, ((size_t)kF * 2 * kDH + kEH + 1) * sizeof(float), stream);

  // the whole GRU (gi precompute + 30 steps) in one persistent launch
  gru_persist<<<NB, BT, 0, stream>>>(gWhh, gbhh, gWih, gbih, a_t, b_t, agru, bar, fptr);

  // expert + eval first layers (streams 126 MB of W1 once, pos+neg fused)
  stage1<<<kF * EXP_SPLIT + EVAL_SPLIT, 512, 0, stream>>>(zpos, zneg, agru, mW1, b_t,
                                                          ipo, eW1, hacc, ehacc, fptr);

  // second layers -> outputs
  stage2<<<kF + 1, 512, 0, stream>>>(hacc, ehacc, mb1, mW2, mb2, eb1, eW2, eb2, out, fptr);
}